// Round 7
// baseline (548.209 us; speedup 1.0000x reference)
//
#include <hip/hip_runtime.h>
#include <hip/hip_fp16.h>

typedef __attribute__((ext_vector_type(8))) _Float16 half8;
typedef __attribute__((ext_vector_type(4))) _Float16 half4;
typedef __attribute__((ext_vector_type(2))) _Float16 half2v;
typedef __attribute__((ext_vector_type(4))) float float4v;

#define LDP2 72  // padded LDS row stride in f16 for BK=64 (144B -> stride 36 banks -> 2-way, free)

// ---------------- degree / CSR build ----------------

__global__ __launch_bounds__(256) void k_deg(const int* __restrict__ dst, int* __restrict__ deg, int E) {
    int e = blockIdx.x * 256 + threadIdx.x;
    if (e < E) atomicAdd(&deg[dst[e]], 1);
}

// ---- parallel exclusive scan of deg -> rowptr (3 phases), dinv fused into phase 1 ----

__global__ __launch_bounds__(256) void k_scan1(const int* __restrict__ deg, int* __restrict__ rowptr,
                                               int* __restrict__ bsum, float* __restrict__ dinv, int N) {
    __shared__ int sm[256];
    const int t = threadIdx.x;
    const int i = blockIdx.x * 256 + t;
    int v = (i < N) ? deg[i] : 0;
    if (i < N) dinv[i] = rsqrtf((float)(v + 1));  // +1 = self-loop
    int x = v;
    sm[t] = x;
    __syncthreads();
#pragma unroll
    for (int off = 1; off < 256; off <<= 1) {
        int y = (t >= off) ? sm[t - off] : 0;
        __syncthreads();
        x += y;
        sm[t] = x;
        __syncthreads();
    }
    if (i < N) rowptr[i] = x - v;      // exclusive within block
    if (t == 255) bsum[blockIdx.x] = x; // block total
}

__global__ __launch_bounds__(256) void k_scan2(int* __restrict__ bsum, int* __restrict__ rowptr, int nb, int N) {
    __shared__ int sm[256];
    const int t = threadIdx.x;
    int v = (t < nb) ? bsum[t] : 0;
    int x = v;
    sm[t] = x;
    __syncthreads();
#pragma unroll
    for (int off = 1; off < 256; off <<= 1) {
        int y = (t >= off) ? sm[t - off] : 0;
        __syncthreads();
        x += y;
        sm[t] = x;
        __syncthreads();
    }
    if (t < nb) bsum[t] = x - v;  // exclusive block offsets
    if (t == 255) rowptr[N] = x;  // grand total = E
}

__global__ __launch_bounds__(256) void k_scan3(int* __restrict__ rowptr, const int* __restrict__ bsum, int N) {
    int i = blockIdx.x * 256 + threadIdx.x;
    if (i < N) rowptr[i] += bsum[blockIdx.x];
}

__global__ __launch_bounds__(256) void k_fill(const int* __restrict__ src, const int* __restrict__ dst,
                                              const int* __restrict__ rowptr, int* __restrict__ rowcnt,
                                              int* __restrict__ csr, int E) {
    int e = blockIdx.x * 256 + threadIdx.x;
    if (e < E) {
        int d = dst[e];
        int pos = rowptr[d] + atomicAdd(&rowcnt[d], 1);
        csr[pos] = src[e];
    }
}

// ---------------- weight prep: transpose + f16 convert ----------------
__global__ __launch_bounds__(256) void k_wt(const float* __restrict__ W1, const float* __restrict__ Wmu,
                                            const float* __restrict__ Wls, _Float16* __restrict__ Wt1,
                                            _Float16* __restrict__ Wct) {
    int b = blockIdx.x;
    int t = threadIdx.x;  // k index
    if (b < 256) {
        Wt1[b * 256 + t] = (_Float16)W1[t * 256 + b];
    } else {
        int j = b - 256;
        float v = (j < 128) ? Wmu[t * 128 + j] : Wls[t * 128 + (j - 128)];
        Wct[j * 256 + t] = (_Float16)v;
    }
}

// ---------------- GEMM: [M x 256] @ [256 x 256], BK=64, reg-prefetch staging ----------------
// f16 node-feature arrays use the FEATURE-TILED layout: [8 tiles][M][32 feats],
// so the agg gather's per-XCD working set (3.2 MB) fits the 4 MB XCD L2.
// AF32=1: A is row-major f32.  AF32=0: A is feature-tiled f16.
// OUTF32=1: write f32 row-major d_out (mu|ls split) + bias.
// OUTF32=0: write feature-tiled f16, rows pre-scaled by dinv[row].
template <int AF32, int OUTF32>
__global__ __launch_bounds__(256) void gemm_k(const void* __restrict__ Aptr, const _Float16* __restrict__ Bt,
                                              const float* __restrict__ bmu, const float* __restrict__ bls,
                                              const float* __restrict__ dinv,
                                              void* __restrict__ outp, int M, size_t split) {
    __shared__ _Float16 As[128 * LDP2];
    __shared__ _Float16 Bs[128 * LDP2];
    const int t = threadIdx.x;
    const int lane = t & 63;
    const int wid = t >> 6;

    // bijective chunked XCD swizzle (assumes xcd = blockIdx.x % 8 round-robin)
    const int nwg = gridDim.x;
    const int wg = blockIdx.x;
    const int q8 = nwg >> 3, r8 = nwg & 7;
    const int xcd = wg & 7, pos = wg >> 3;
    const int v = (xcd < r8) ? (xcd * (q8 + 1) + pos) : (r8 * (q8 + 1) + (xcd - r8) * q8 + pos);
    const int bm = (v >> 1) * 128;
    const int bn = (v & 1) * 128;

    const int wm = (wid & 1) * 64;
    const int wn = (wid >> 1) * 64;

    float4v acc[4][4];
#pragma unroll
    for (int i = 0; i < 4; i++)
#pragma unroll
        for (int j = 0; j < 4; j++) acc[i][j] = (float4v){0.f, 0.f, 0.f, 0.f};

    // prefetch registers
    float4v ar32[8];
    half8 ar16[4];
    half8 br[4];

    const int a32row = t >> 1;
    const int a32ko = (t & 1) * 32;

    auto load_regs = [&](int kt) {
        if (AF32) {
            const float* A = (const float*)Aptr;
            int gr = bm + a32row; if (gr >= M) gr = M - 1;
            const float4v* p = (const float4v*)(A + (size_t)gr * 256 + kt + a32ko);
#pragma unroll
            for (int q = 0; q < 8; q++) ar32[q] = p[q];
        } else {
            const _Float16* A = (const _Float16*)Aptr;
#pragma unroll
            for (int m = 0; m < 4; m++) {
                int u = m * 256 + t;
                int row = u >> 3, k8 = (u & 7) * 8;
                int gr = bm + row; if (gr >= M) gr = M - 1;
                int k = kt + k8;  // feature index; tiled address
                ar16[m] = *(const half8*)(A + (size_t)(k >> 5) * M * 32 + (size_t)gr * 32 + (k & 31));
            }
        }
#pragma unroll
        for (int m = 0; m < 4; m++) {
            int u = m * 256 + t;
            int row = u >> 3, k8 = (u & 7) * 8;
            br[m] = *(const half8*)(Bt + (size_t)(bn + row) * 256 + kt + k8);
        }
    };

    auto write_lds = [&]() {
        if (AF32) {
#pragma unroll
            for (int q = 0; q < 4; q++) {
                half8 h;
#pragma unroll
                for (int j = 0; j < 4; j++) { h[j] = (_Float16)ar32[2 * q][j]; h[4 + j] = (_Float16)ar32[2 * q + 1][j]; }
                *(half8*)&As[a32row * LDP2 + a32ko + q * 8] = h;
            }
        } else {
#pragma unroll
            for (int m = 0; m < 4; m++) {
                int u = m * 256 + t;
                int row = u >> 3, k8 = (u & 7) * 8;
                *(half8*)&As[row * LDP2 + k8] = ar16[m];
            }
        }
#pragma unroll
        for (int m = 0; m < 4; m++) {
            int u = m * 256 + t;
            int row = u >> 3, k8 = (u & 7) * 8;
            *(half8*)&Bs[row * LDP2 + k8] = br[m];
        }
    };

    load_regs(0);
#pragma unroll
    for (int it = 0; it < 4; it++) {
        if (it > 0) __syncthreads();
        write_lds();
        __syncthreads();
        if (it < 3) load_regs((it + 1) * 64);  // next-tile loads hidden under MFMA

        const int kg = (lane >> 4) * 8;
        const int fr = lane & 15;
#pragma unroll
        for (int kk = 0; kk < 64; kk += 32) {
            half8 af[4], bf[4];
#pragma unroll
            for (int f = 0; f < 4; f++) af[f] = *(const half8*)&As[(wm + f * 16 + fr) * LDP2 + kk + kg];
#pragma unroll
            for (int f = 0; f < 4; f++) bf[f] = *(const half8*)&Bs[(wn + f * 16 + fr) * LDP2 + kk + kg];
#pragma unroll
            for (int i = 0; i < 4; i++)
#pragma unroll
                for (int j = 0; j < 4; j++)
                    acc[i][j] = __builtin_amdgcn_mfma_f32_16x16x32_f16(af[i], bf[j], acc[i][j], 0, 0, 0);
        }
    }

    // ---- epilogue: D mapping col=lane&15, row=(lane>>4)*4+reg ----
    const int fc = lane & 15;
    const int rq = (lane >> 4) * 4;
    if (OUTF32) {
        float* out = (float*)outp;
#pragma unroll
        for (int i = 0; i < 4; i++) {
#pragma unroll
            for (int j = 0; j < 4; j++) {
                int col = bn + wn + j * 16 + fc;
                float bias = (col < 128) ? bmu[col] : bls[col - 128];
#pragma unroll
                for (int r = 0; r < 4; r++) {
                    int row = bm + wm + i * 16 + rq + r;
                    if (row < M) {
                        size_t o = (col < 128) ? ((size_t)row * 128 + col)
                                               : (split + (size_t)row * 128 + (col - 128));
                        out[o] = acc[i][j][r] + bias;
                    }
                }
            }
        }
    } else {
        _Float16* out = (_Float16*)outp;
#pragma unroll
        for (int i = 0; i < 4; i++) {
#pragma unroll
            for (int r = 0; r < 4; r++) {
                int row = bm + wm + i * 16 + rq + r;
                if (row < M) {
                    float sc = dinv[row];  // pre-scale rows by dinv -> agg loop needs no dinv[s]
#pragma unroll
                    for (int j = 0; j < 4; j++) {
                        int col = bn + wn + j * 16 + fc;
                        out[(size_t)(col >> 5) * M * 32 + (size_t)row * 32 + (col & 31)] =
                            (_Float16)(acc[i][j][r] * sc);
                    }
                }
            }
        }
    }
}

// ---------------- feature-tiled aggregation ----------------
// in/out are [8][N][32] f16, rows pre-scaled by dinv. tile = blockIdx.x & 7 ->
// round-robin dispatch pins tile t to XCD t; per-XCD gather set = N*32*2B = 3.2MB < 4MB L2.
// Wave = 1 node: 4 edge slots x 16 lanes x half2. xor-reduce over lane bits 4,5.
// MODE 1: out = relu(acc*dd + bias)*dd   MODE 0: out = acc*dd
template <int MODE>
__global__ __launch_bounds__(256) void k_agg_t(const _Float16* __restrict__ in, _Float16* __restrict__ out,
                                               const float* __restrict__ dinv, const int* __restrict__ rowptr,
                                               const int* __restrict__ csr, const float* __restrict__ bias,
                                               int N) {
    const int tile = blockIdx.x & 7;
    const int g = (blockIdx.x >> 3) * 4 + (threadIdx.x >> 6);
    if (g >= N) return;
    const int lane = threadIdx.x & 63;
    const int eg = lane >> 4;   // edge slot 0..3
    const int fl = lane & 15;   // feature-pair index
    const _Float16* __restrict__ tin = in + (size_t)tile * N * 32;

    const int beg = rowptr[g], end = rowptr[g + 1];
    float a0 = 0.f, a1 = 0.f;
    for (int e = beg + eg; e < end; e += 4) {
        int s = csr[e];
        half2v v = *(const half2v*)(tin + (size_t)s * 32 + fl * 2);
        a0 += (float)v[0];
        a1 += (float)v[1];
    }
    a0 += __shfl_xor(a0, 16); a0 += __shfl_xor(a0, 32);
    a1 += __shfl_xor(a1, 16); a1 += __shfl_xor(a1, 32);

    if (eg == 0) {
        half2v sv = *(const half2v*)(tin + (size_t)g * 32 + fl * 2);  // self (pre-scaled)
        a0 += (float)sv[0];
        a1 += (float)sv[1];
        const float dd = dinv[g];
        half2v o;
        if (MODE) {
            float b0 = bias[tile * 32 + fl * 2];
            float b1 = bias[tile * 32 + fl * 2 + 1];
            o[0] = (_Float16)(fmaxf(a0 * dd + b0, 0.f) * dd);
            o[1] = (_Float16)(fmaxf(a1 * dd + b1, 0.f) * dd);
        } else {
            o[0] = (_Float16)(a0 * dd);
            o[1] = (_Float16)(a1 * dd);
        }
        *(half2v*)(out + (size_t)tile * N * 32 + (size_t)g * 32 + fl * 2) = o;
    }
}

// ---------------- launch ----------------

extern "C" void kernel_launch(void* const* d_in, const int* in_sizes, int n_in,
                              void* d_out, int out_size, void* d_ws, size_t ws_size,
                              hipStream_t stream) {
    const float* x   = (const float*)d_in[0];
    const int*   ei  = (const int*)d_in[1];
    const float* W1  = (const float*)d_in[2];
    const float* b1  = (const float*)d_in[3];
    const float* Wmu = (const float*)d_in[4];
    const float* bmu = (const float*)d_in[5];
    const float* Wls = (const float*)d_in[6];
    const float* bls = (const float*)d_in[7];
    const int N = in_sizes[0] / 256;
    const int E = in_sizes[1] / 2;
    const int* esrc = ei;
    const int* edst = ei + E;

    char* ws = (char*)d_ws;
    size_t off = 0;
    auto alloc = [&](size_t bytes) -> void* {
        void* p = ws + off;
        off += (bytes + 255) & ~(size_t)255;
        return p;
    };
    _Float16* h1  = (_Float16*)alloc((size_t)N * 256 * 2);  // tiled h1s (scaled); reused as g
    _Float16* hb  = (_Float16*)alloc((size_t)N * 256 * 2);  // tiled hbs (scaled)
    _Float16* Wt1 = (_Float16*)alloc(256 * 256 * 2);
    _Float16* Wct = (_Float16*)alloc(256 * 256 * 2);
    float* dinv   = (float*)alloc((size_t)N * 4);
    int* degcnt   = (int*)alloc((size_t)N * 2 * 4);  // [deg | rowcnt] contiguous -> one memset
    int* deg      = degcnt;
    int* rowcnt   = degcnt + N;
    int* rowptr   = (int*)alloc((size_t)(N + 1) * 4);
    int* bsum     = (int*)alloc(256 * 4);
    int* csr      = (int*)alloc((size_t)E * 4);

    const int nb = (N + 255) / 256;  // scan blocks (<=256)

    hipMemsetAsync(degcnt, 0, (size_t)N * 2 * 4, stream);

    k_deg<<<(E + 255) / 256, 256, 0, stream>>>(edst, deg, E);
    k_scan1<<<nb, 256, 0, stream>>>(deg, rowptr, bsum, dinv, N);
    k_scan2<<<1, 256, 0, stream>>>(bsum, rowptr, nb, N);
    k_scan3<<<nb, 256, 0, stream>>>(rowptr, bsum, N);
    k_fill<<<(E + 255) / 256, 256, 0, stream>>>(esrc, edst, rowptr, rowcnt, csr, E);
    k_wt<<<512, 256, 0, stream>>>(W1, Wmu, Wls, Wt1, Wct);

    const int nbm = (N + 127) / 128;
    const int nba = 8 * ((N + 3) / 4);
    gemm_k<1, 0><<<nbm * 2, 256, 0, stream>>>(x, Wt1, nullptr, nullptr, dinv, h1, N, 0);
    k_agg_t<1><<<nba, 256, 0, stream>>>(h1, hb, dinv, rowptr, csr, b1, N);
    k_agg_t<0><<<nba, 256, 0, stream>>>(hb, h1, dinv, rowptr, csr, nullptr, N);
    gemm_k<0, 1><<<nbm * 2, 256, 0, stream>>>(h1, Wct, bmu, bls, nullptr, d_out, N, (size_t)N * 128);
}

// Round 8
// 342.171 us; speedup vs baseline: 1.6021x; 1.6021x over previous
//
#include <hip/hip_runtime.h>
#include <hip/hip_fp16.h>

typedef __attribute__((ext_vector_type(8))) _Float16 half8;
typedef __attribute__((ext_vector_type(4))) _Float16 half4;
typedef __attribute__((ext_vector_type(4))) float float4v;

#define LDP2 72  // padded LDS row stride in f16 for BK=64 (144B -> stride 36 banks -> 2-way, free)

// ---------------- degree / CSR build ----------------

__global__ __launch_bounds__(256) void k_deg(const int* __restrict__ dst, int* __restrict__ deg, int E) {
    int e = blockIdx.x * 256 + threadIdx.x;
    if (e < E) atomicAdd(&deg[dst[e]], 1);
}

// ---- parallel exclusive scan of deg -> rowptr (3 phases), dinv fused into phase 1 ----

__global__ __launch_bounds__(256) void k_scan1(const int* __restrict__ deg, int* __restrict__ rowptr,
                                               int* __restrict__ bsum, float* __restrict__ dinv, int N) {
    __shared__ int sm[256];
    const int t = threadIdx.x;
    const int i = blockIdx.x * 256 + t;
    int v = (i < N) ? deg[i] : 0;
    if (i < N) dinv[i] = rsqrtf((float)(v + 1));  // +1 = self-loop
    int x = v;
    sm[t] = x;
    __syncthreads();
#pragma unroll
    for (int off = 1; off < 256; off <<= 1) {
        int y = (t >= off) ? sm[t - off] : 0;
        __syncthreads();
        x += y;
        sm[t] = x;
        __syncthreads();
    }
    if (i < N) rowptr[i] = x - v;      // exclusive within block
    if (t == 255) bsum[blockIdx.x] = x; // block total
}

__global__ __launch_bounds__(256) void k_scan2(int* __restrict__ bsum, int* __restrict__ rowptr, int nb, int N) {
    __shared__ int sm[256];
    const int t = threadIdx.x;
    int v = (t < nb) ? bsum[t] : 0;
    int x = v;
    sm[t] = x;
    __syncthreads();
#pragma unroll
    for (int off = 1; off < 256; off <<= 1) {
        int y = (t >= off) ? sm[t - off] : 0;
        __syncthreads();
        x += y;
        sm[t] = x;
        __syncthreads();
    }
    if (t < nb) bsum[t] = x - v;  // exclusive block offsets
    if (t == 255) rowptr[N] = x;  // grand total = E
}

__global__ __launch_bounds__(256) void k_scan3(int* __restrict__ rowptr, const int* __restrict__ bsum, int N) {
    int i = blockIdx.x * 256 + threadIdx.x;
    if (i < N) rowptr[i] += bsum[blockIdx.x];
}

__global__ __launch_bounds__(256) void k_fill(const int* __restrict__ src, const int* __restrict__ dst,
                                              const int* __restrict__ rowptr, int* __restrict__ rowcnt,
                                              int* __restrict__ csr, int E) {
    int e = blockIdx.x * 256 + threadIdx.x;
    if (e < E) {
        int d = dst[e];
        int pos = rowptr[d] + atomicAdd(&rowcnt[d], 1);
        csr[pos] = src[e];
    }
}

// ---------------- weight prep: transpose + f16 convert ----------------
__global__ __launch_bounds__(256) void k_wt(const float* __restrict__ W1, const float* __restrict__ Wmu,
                                            const float* __restrict__ Wls, _Float16* __restrict__ Wt1,
                                            _Float16* __restrict__ Wct) {
    int b = blockIdx.x;
    int t = threadIdx.x;  // k index
    if (b < 256) {
        Wt1[b * 256 + t] = (_Float16)W1[t * 256 + b];
    } else {
        int j = b - 256;
        float v = (j < 128) ? Wmu[t * 128 + j] : Wls[t * 128 + (j - 128)];
        Wct[j * 256 + t] = (_Float16)v;
    }
}

// ---------------- GEMM: [M x 256] @ [256 x 256], BK=64, reg-prefetch staging ----------------
// f16 node-feature arrays use the FEATURE-TILED layout: [8 tiles][M][32 feats],
// so the agg gather's per-XCD working set (3.2 MB) fits the 4 MB XCD L2.
// AF32=1: A is row-major f32.  AF32=0: A is feature-tiled f16.
// OUTF32=1: write f32 row-major d_out (mu|ls split) + bias.
// OUTF32=0: write feature-tiled f16, rows pre-scaled by dinv[row].
template <int AF32, int OUTF32>
__global__ __launch_bounds__(256) void gemm_k(const void* __restrict__ Aptr, const _Float16* __restrict__ Bt,
                                              const float* __restrict__ bmu, const float* __restrict__ bls,
                                              const float* __restrict__ dinv,
                                              void* __restrict__ outp, int M, size_t split) {
    __shared__ _Float16 As[128 * LDP2];
    __shared__ _Float16 Bs[128 * LDP2];
    const int t = threadIdx.x;
    const int lane = t & 63;
    const int wid = t >> 6;

    // bijective chunked XCD swizzle (assumes xcd = blockIdx.x % 8 round-robin)
    const int nwg = gridDim.x;
    const int wg = blockIdx.x;
    const int q8 = nwg >> 3, r8 = nwg & 7;
    const int xcd = wg & 7, pos = wg >> 3;
    const int v = (xcd < r8) ? (xcd * (q8 + 1) + pos) : (r8 * (q8 + 1) + (xcd - r8) * q8 + pos);
    const int bm = (v >> 1) * 128;
    const int bn = (v & 1) * 128;

    const int wm = (wid & 1) * 64;
    const int wn = (wid >> 1) * 64;

    float4v acc[4][4];
#pragma unroll
    for (int i = 0; i < 4; i++)
#pragma unroll
        for (int j = 0; j < 4; j++) acc[i][j] = (float4v){0.f, 0.f, 0.f, 0.f};

    // prefetch registers
    float4v ar32[8];
    half8 ar16[4];
    half8 br[4];

    const int a32row = t >> 1;
    const int a32ko = (t & 1) * 32;

    auto load_regs = [&](int kt) {
        if (AF32) {
            const float* A = (const float*)Aptr;
            int gr = bm + a32row; if (gr >= M) gr = M - 1;
            const float4v* p = (const float4v*)(A + (size_t)gr * 256 + kt + a32ko);
#pragma unroll
            for (int q = 0; q < 8; q++) ar32[q] = p[q];
        } else {
            const _Float16* A = (const _Float16*)Aptr;
#pragma unroll
            for (int m = 0; m < 4; m++) {
                int u = m * 256 + t;
                int row = u >> 3, k8 = (u & 7) * 8;
                int gr = bm + row; if (gr >= M) gr = M - 1;
                int k = kt + k8;  // feature index; tiled address
                ar16[m] = *(const half8*)(A + (size_t)(k >> 5) * M * 32 + (size_t)gr * 32 + (k & 31));
            }
        }
#pragma unroll
        for (int m = 0; m < 4; m++) {
            int u = m * 256 + t;
            int row = u >> 3, k8 = (u & 7) * 8;
            br[m] = *(const half8*)(Bt + (size_t)(bn + row) * 256 + kt + k8);
        }
    };

    auto write_lds = [&]() {
        if (AF32) {
#pragma unroll
            for (int q = 0; q < 4; q++) {
                half8 h;
#pragma unroll
                for (int j = 0; j < 4; j++) { h[j] = (_Float16)ar32[2 * q][j]; h[4 + j] = (_Float16)ar32[2 * q + 1][j]; }
                *(half8*)&As[a32row * LDP2 + a32ko + q * 8] = h;
            }
        } else {
#pragma unroll
            for (int m = 0; m < 4; m++) {
                int u = m * 256 + t;
                int row = u >> 3, k8 = (u & 7) * 8;
                *(half8*)&As[row * LDP2 + k8] = ar16[m];
            }
        }
#pragma unroll
        for (int m = 0; m < 4; m++) {
            int u = m * 256 + t;
            int row = u >> 3, k8 = (u & 7) * 8;
            *(half8*)&Bs[row * LDP2 + k8] = br[m];
        }
    };

    load_regs(0);
#pragma unroll
    for (int it = 0; it < 4; it++) {
        if (it > 0) __syncthreads();
        write_lds();
        __syncthreads();
        if (it < 3) load_regs((it + 1) * 64);  // next-tile loads hidden under MFMA

        const int kg = (lane >> 4) * 8;
        const int fr = lane & 15;
#pragma unroll
        for (int kk = 0; kk < 64; kk += 32) {
            half8 af[4], bf[4];
#pragma unroll
            for (int f = 0; f < 4; f++) af[f] = *(const half8*)&As[(wm + f * 16 + fr) * LDP2 + kk + kg];
#pragma unroll
            for (int f = 0; f < 4; f++) bf[f] = *(const half8*)&Bs[(wn + f * 16 + fr) * LDP2 + kk + kg];
#pragma unroll
            for (int i = 0; i < 4; i++)
#pragma unroll
                for (int j = 0; j < 4; j++)
                    acc[i][j] = __builtin_amdgcn_mfma_f32_16x16x32_f16(af[i], bf[j], acc[i][j], 0, 0, 0);
        }
    }

    // ---- epilogue: D mapping col=lane&15, row=(lane>>4)*4+reg ----
    const int fc = lane & 15;
    const int rq = (lane >> 4) * 4;
    if (OUTF32) {
        float* out = (float*)outp;
#pragma unroll
        for (int i = 0; i < 4; i++) {
#pragma unroll
            for (int j = 0; j < 4; j++) {
                int col = bn + wn + j * 16 + fc;
                float bias = (col < 128) ? bmu[col] : bls[col - 128];
#pragma unroll
                for (int r = 0; r < 4; r++) {
                    int row = bm + wm + i * 16 + rq + r;
                    if (row < M) {
                        size_t o = (col < 128) ? ((size_t)row * 128 + col)
                                               : (split + (size_t)row * 128 + (col - 128));
                        out[o] = acc[i][j][r] + bias;
                    }
                }
            }
        }
    } else {
        _Float16* out = (_Float16*)outp;
#pragma unroll
        for (int i = 0; i < 4; i++) {
#pragma unroll
            for (int r = 0; r < 4; r++) {
                int row = bm + wm + i * 16 + rq + r;
                if (row < M) {
                    float sc = dinv[row];  // pre-scale rows by dinv -> agg loop needs no dinv[s]
#pragma unroll
                    for (int j = 0; j < 4; j++) {
                        int col = bn + wn + j * 16 + fc;
                        out[(size_t)(col >> 5) * M * 32 + (size_t)row * 32 + (col & 31)] =
                            (_Float16)(acc[i][j][r] * sc);
                    }
                }
            }
        }
    }
}

// ---------------- feature-tiled aggregation, 4 lanes/node x 16 nodes/wave ----------------
// in/out are [8][N][32] f16, rows pre-scaled by dinv. tile = blockIdx.x & 7 ->
// round-robin dispatch pins tile t to XCD t; per-XCD gather set = N*32*2B = 3.2MB < 4MB L2.
// Lane owns 8 features (16B); node = tid>>2, fq = tid&3. No cross-lane reduce.
// MODE 1: out = relu(acc*dd + bias)*dd   MODE 0: out = acc*dd
template <int MODE>
__global__ __launch_bounds__(256) void k_agg_t(const _Float16* __restrict__ in, _Float16* __restrict__ out,
                                               const float* __restrict__ dinv, const int* __restrict__ rowptr,
                                               const int* __restrict__ csr, const float* __restrict__ bias,
                                               int N) {
    const int tile = blockIdx.x & 7;
    const int g = (blockIdx.x >> 3) * 64 + (threadIdx.x >> 2);
    if (g >= N) return;
    const int fq = threadIdx.x & 3;  // feature-quarter: 8 f16 = 16B
    const _Float16* __restrict__ tin = in + (size_t)tile * N * 32 + fq * 8;

    const int beg = rowptr[g], end = rowptr[g + 1];

    float acc[8];
    {
        half8 sv = *(const half8*)(tin + (size_t)g * 32);  // self (pre-scaled)
#pragma unroll
        for (int j = 0; j < 8; j++) acc[j] = (float)sv[j];
    }
#pragma unroll 4
    for (int e = beg; e < end; ++e) {
        int s = csr[e];
        half8 v = *(const half8*)(tin + (size_t)s * 32);
#pragma unroll
        for (int j = 0; j < 8; j++) acc[j] += (float)v[j];
    }

    const float dd = dinv[g];
    half8 o;
    if (MODE) {
        const float4v* bp = (const float4v*)(bias + tile * 32 + fq * 8);
        float4v b0 = bp[0], b1 = bp[1];
#pragma unroll
        for (int j = 0; j < 4; j++) {
            o[j] = (_Float16)(fmaxf(acc[j] * dd + b0[j], 0.f) * dd);
            o[4 + j] = (_Float16)(fmaxf(acc[4 + j] * dd + b1[j], 0.f) * dd);
        }
    } else {
#pragma unroll
        for (int j = 0; j < 8; j++) o[j] = (_Float16)(acc[j] * dd);
    }
    *(half8*)(out + (size_t)tile * N * 32 + (size_t)g * 32 + fq * 8) = o;
}

// ---------------- launch ----------------

extern "C" void kernel_launch(void* const* d_in, const int* in_sizes, int n_in,
                              void* d_out, int out_size, void* d_ws, size_t ws_size,
                              hipStream_t stream) {
    const float* x   = (const float*)d_in[0];
    const int*   ei  = (const int*)d_in[1];
    const float* W1  = (const float*)d_in[2];
    const float* b1  = (const float*)d_in[3];
    const float* Wmu = (const float*)d_in[4];
    const float* bmu = (const float*)d_in[5];
    const float* Wls = (const float*)d_in[6];
    const float* bls = (const float*)d_in[7];
    const int N = in_sizes[0] / 256;
    const int E = in_sizes[1] / 2;
    const int* esrc = ei;
    const int* edst = ei + E;

    char* ws = (char*)d_ws;
    size_t off = 0;
    auto alloc = [&](size_t bytes) -> void* {
        void* p = ws + off;
        off += (bytes + 255) & ~(size_t)255;
        return p;
    };
    _Float16* h1  = (_Float16*)alloc((size_t)N * 256 * 2);  // tiled h1s (scaled); reused as g
    _Float16* hb  = (_Float16*)alloc((size_t)N * 256 * 2);  // tiled hbs (scaled)
    _Float16* Wt1 = (_Float16*)alloc(256 * 256 * 2);
    _Float16* Wct = (_Float16*)alloc(256 * 256 * 2);
    float* dinv   = (float*)alloc((size_t)N * 4);
    int* degcnt   = (int*)alloc((size_t)N * 2 * 4);  // [deg | rowcnt] contiguous -> one memset
    int* deg      = degcnt;
    int* rowcnt   = degcnt + N;
    int* rowptr   = (int*)alloc((size_t)(N + 1) * 4);
    int* bsum     = (int*)alloc(256 * 4);
    int* csr      = (int*)alloc((size_t)E * 4);

    const int nb = (N + 255) / 256;  // scan blocks (<=256)

    hipMemsetAsync(degcnt, 0, (size_t)N * 2 * 4, stream);

    k_deg<<<(E + 255) / 256, 256, 0, stream>>>(edst, deg, E);
    k_scan1<<<nb, 256, 0, stream>>>(deg, rowptr, bsum, dinv, N);
    k_scan2<<<1, 256, 0, stream>>>(bsum, rowptr, nb, N);
    k_scan3<<<nb, 256, 0, stream>>>(rowptr, bsum, N);
    k_fill<<<(E + 255) / 256, 256, 0, stream>>>(esrc, edst, rowptr, rowcnt, csr, E);
    k_wt<<<512, 256, 0, stream>>>(W1, Wmu, Wls, Wt1, Wct);

    const int nbm = (N + 127) / 128;
    const int nba = 8 * ((N + 63) / 64);
    gemm_k<1, 0><<<nbm * 2, 256, 0, stream>>>(x, Wt1, nullptr, nullptr, dinv, h1, N, 0);
    k_agg_t<1><<<nba, 256, 0, stream>>>(h1, hb, dinv, rowptr, csr, b1, N);
    k_agg_t<0><<<nba, 256, 0, stream>>>(hb, h1, dinv, rowptr, csr, nullptr, N);
    gemm_k<0, 1><<<nbm * 2, 256, 0, stream>>>(h1, Wct, bmu, bls, nullptr, d_out, N, (size_t)N * 128);
}

// Round 9
// 331.141 us; speedup vs baseline: 1.6555x; 1.0333x over previous
//
#include <hip/hip_runtime.h>
#include <hip/hip_fp16.h>

typedef __attribute__((ext_vector_type(8))) _Float16 half8;
typedef __attribute__((ext_vector_type(4))) _Float16 half4;
typedef __attribute__((ext_vector_type(4))) float float4v;

#define LDP2 72  // padded LDS row stride in f16 for BK=64 (144B -> stride 36 banks -> 2-way, free)

// ---------------- degree / CSR build (dst-range partitioned per XCD) ----------------
// part = blockIdx & 7 -> round-robin XCD pinning. Each part streams the full edge
// list but only touches dst in its own N/8 range: atomics hit a 25KB L2-local slice,
// csr writes fall in a contiguous per-XCD span (full-line merge, no cross-XCD dirty
// line sharing -> kills the 17x write amplification seen in round 8).

__global__ __launch_bounds__(256) void k_deg(const int* __restrict__ dst, int* __restrict__ deg,
                                             int E, int N) {
    const int part = blockIdx.x & 7;
    const int e = (blockIdx.x >> 3) * 256 + threadIdx.x;
    if (e >= E) return;
    const int lo = (int)(((long long)part * N) >> 3);
    const int hi = (int)(((long long)(part + 1) * N) >> 3);
    int d = dst[e];
    if (d >= lo && d < hi) atomicAdd(&deg[d], 1);
}

__global__ __launch_bounds__(256) void k_fill(const int* __restrict__ src, const int* __restrict__ dst,
                                              const int* __restrict__ rowptr, int* __restrict__ rowcnt,
                                              int* __restrict__ csr, int E, int N) {
    const int part = blockIdx.x & 7;
    const int e = (blockIdx.x >> 3) * 256 + threadIdx.x;
    if (e >= E) return;
    const int lo = (int)(((long long)part * N) >> 3);
    const int hi = (int)(((long long)(part + 1) * N) >> 3);
    int d = dst[e];
    if (d >= lo && d < hi) {
        int pos = rowptr[d] + atomicAdd(&rowcnt[d], 1);
        csr[pos] = src[e];
    }
}

// ---- parallel exclusive scan of deg -> rowptr (3 phases), dinv fused into phase 1 ----

__global__ __launch_bounds__(256) void k_scan1(const int* __restrict__ deg, int* __restrict__ rowptr,
                                               int* __restrict__ bsum, float* __restrict__ dinv, int N) {
    __shared__ int sm[256];
    const int t = threadIdx.x;
    const int i = blockIdx.x * 256 + t;
    int v = (i < N) ? deg[i] : 0;
    if (i < N) dinv[i] = rsqrtf((float)(v + 1));  // +1 = self-loop
    int x = v;
    sm[t] = x;
    __syncthreads();
#pragma unroll
    for (int off = 1; off < 256; off <<= 1) {
        int y = (t >= off) ? sm[t - off] : 0;
        __syncthreads();
        x += y;
        sm[t] = x;
        __syncthreads();
    }
    if (i < N) rowptr[i] = x - v;      // exclusive within block
    if (t == 255) bsum[blockIdx.x] = x; // block total
}

__global__ __launch_bounds__(256) void k_scan2(int* __restrict__ bsum, int* __restrict__ rowptr, int nb, int N) {
    __shared__ int sm[256];
    const int t = threadIdx.x;
    int v = (t < nb) ? bsum[t] : 0;
    int x = v;
    sm[t] = x;
    __syncthreads();
#pragma unroll
    for (int off = 1; off < 256; off <<= 1) {
        int y = (t >= off) ? sm[t - off] : 0;
        __syncthreads();
        x += y;
        sm[t] = x;
        __syncthreads();
    }
    if (t < nb) bsum[t] = x - v;  // exclusive block offsets
    if (t == 255) rowptr[N] = x;  // grand total = E
}

__global__ __launch_bounds__(256) void k_scan3(int* __restrict__ rowptr, const int* __restrict__ bsum, int N) {
    int i = blockIdx.x * 256 + threadIdx.x;
    if (i < N) rowptr[i] += bsum[blockIdx.x];
}

// ---------------- weight prep: transpose + f16 convert ----------------
__global__ __launch_bounds__(256) void k_wt(const float* __restrict__ W1, const float* __restrict__ Wmu,
                                            const float* __restrict__ Wls, _Float16* __restrict__ Wt1,
                                            _Float16* __restrict__ Wct) {
    int b = blockIdx.x;
    int t = threadIdx.x;  // k index
    if (b < 256) {
        Wt1[b * 256 + t] = (_Float16)W1[t * 256 + b];
    } else {
        int j = b - 256;
        float v = (j < 128) ? Wmu[t * 128 + j] : Wls[t * 128 + (j - 128)];
        Wct[j * 256 + t] = (_Float16)v;
    }
}

// ---------------- GEMM: [M x 256] @ [256 x 256], BK=64, reg-prefetch staging ----------------
// f16 node-feature arrays use the FEATURE-TILED layout: [8 tiles][M][32 feats],
// so the agg gather's per-XCD working set (3.2 MB) fits the 4 MB XCD L2.
// AF32=1: A is row-major f32.  AF32=0: A is feature-tiled f16.
// OUTF32=1: write f32 row-major d_out (mu|ls split) + bias.
// OUTF32=0: write feature-tiled f16, rows pre-scaled by dinv[row].
template <int AF32, int OUTF32>
__global__ __launch_bounds__(256) void gemm_k(const void* __restrict__ Aptr, const _Float16* __restrict__ Bt,
                                              const float* __restrict__ bmu, const float* __restrict__ bls,
                                              const float* __restrict__ dinv,
                                              void* __restrict__ outp, int M, size_t split) {
    __shared__ _Float16 As[128 * LDP2];
    __shared__ _Float16 Bs[128 * LDP2];
    const int t = threadIdx.x;
    const int lane = t & 63;
    const int wid = t >> 6;

    // bijective chunked XCD swizzle (assumes xcd = blockIdx.x % 8 round-robin)
    const int nwg = gridDim.x;
    const int wg = blockIdx.x;
    const int q8 = nwg >> 3, r8 = nwg & 7;
    const int xcd = wg & 7, pos = wg >> 3;
    const int v = (xcd < r8) ? (xcd * (q8 + 1) + pos) : (r8 * (q8 + 1) + (xcd - r8) * q8 + pos);
    const int bm = (v >> 1) * 128;
    const int bn = (v & 1) * 128;

    const int wm = (wid & 1) * 64;
    const int wn = (wid >> 1) * 64;

    float4v acc[4][4];
#pragma unroll
    for (int i = 0; i < 4; i++)
#pragma unroll
        for (int j = 0; j < 4; j++) acc[i][j] = (float4v){0.f, 0.f, 0.f, 0.f};

    // prefetch registers
    float4v ar32[8];
    half8 ar16[4];
    half8 br[4];

    const int a32row = t >> 1;
    const int a32ko = (t & 1) * 32;

    auto load_regs = [&](int kt) {
        if (AF32) {
            const float* A = (const float*)Aptr;
            int gr = bm + a32row; if (gr >= M) gr = M - 1;
            const float4v* p = (const float4v*)(A + (size_t)gr * 256 + kt + a32ko);
#pragma unroll
            for (int q = 0; q < 8; q++) ar32[q] = p[q];
        } else {
            const _Float16* A = (const _Float16*)Aptr;
#pragma unroll
            for (int m = 0; m < 4; m++) {
                int u = m * 256 + t;
                int row = u >> 3, k8 = (u & 7) * 8;
                int gr = bm + row; if (gr >= M) gr = M - 1;
                int k = kt + k8;  // feature index; tiled address
                ar16[m] = *(const half8*)(A + (size_t)(k >> 5) * M * 32 + (size_t)gr * 32 + (k & 31));
            }
        }
#pragma unroll
        for (int m = 0; m < 4; m++) {
            int u = m * 256 + t;
            int row = u >> 3, k8 = (u & 7) * 8;
            br[m] = *(const half8*)(Bt + (size_t)(bn + row) * 256 + kt + k8);
        }
    };

    auto write_lds = [&]() {
        if (AF32) {
#pragma unroll
            for (int q = 0; q < 4; q++) {
                half8 h;
#pragma unroll
                for (int j = 0; j < 4; j++) { h[j] = (_Float16)ar32[2 * q][j]; h[4 + j] = (_Float16)ar32[2 * q + 1][j]; }
                *(half8*)&As[a32row * LDP2 + a32ko + q * 8] = h;
            }
        } else {
#pragma unroll
            for (int m = 0; m < 4; m++) {
                int u = m * 256 + t;
                int row = u >> 3, k8 = (u & 7) * 8;
                *(half8*)&As[row * LDP2 + k8] = ar16[m];
            }
        }
#pragma unroll
        for (int m = 0; m < 4; m++) {
            int u = m * 256 + t;
            int row = u >> 3, k8 = (u & 7) * 8;
            *(half8*)&Bs[row * LDP2 + k8] = br[m];
        }
    };

    load_regs(0);
#pragma unroll
    for (int it = 0; it < 4; it++) {
        if (it > 0) __syncthreads();
        write_lds();
        __syncthreads();
        if (it < 3) load_regs((it + 1) * 64);  // next-tile loads hidden under MFMA

        const int kg = (lane >> 4) * 8;
        const int fr = lane & 15;
#pragma unroll
        for (int kk = 0; kk < 64; kk += 32) {
            half8 af[4], bf[4];
#pragma unroll
            for (int f = 0; f < 4; f++) af[f] = *(const half8*)&As[(wm + f * 16 + fr) * LDP2 + kk + kg];
#pragma unroll
            for (int f = 0; f < 4; f++) bf[f] = *(const half8*)&Bs[(wn + f * 16 + fr) * LDP2 + kk + kg];
#pragma unroll
            for (int i = 0; i < 4; i++)
#pragma unroll
                for (int j = 0; j < 4; j++)
                    acc[i][j] = __builtin_amdgcn_mfma_f32_16x16x32_f16(af[i], bf[j], acc[i][j], 0, 0, 0);
        }
    }

    // ---- epilogue: D mapping col=lane&15, row=(lane>>4)*4+reg ----
    const int fc = lane & 15;
    const int rq = (lane >> 4) * 4;
    if (OUTF32) {
        float* out = (float*)outp;
#pragma unroll
        for (int i = 0; i < 4; i++) {
#pragma unroll
            for (int j = 0; j < 4; j++) {
                int col = bn + wn + j * 16 + fc;
                float bias = (col < 128) ? bmu[col] : bls[col - 128];
#pragma unroll
                for (int r = 0; r < 4; r++) {
                    int row = bm + wm + i * 16 + rq + r;
                    if (row < M) {
                        size_t o = (col < 128) ? ((size_t)row * 128 + col)
                                               : (split + (size_t)row * 128 + (col - 128));
                        out[o] = acc[i][j][r] + bias;
                    }
                }
            }
        }
    } else {
        _Float16* out = (_Float16*)outp;
#pragma unroll
        for (int i = 0; i < 4; i++) {
#pragma unroll
            for (int r = 0; r < 4; r++) {
                int row = bm + wm + i * 16 + rq + r;
                if (row < M) {
                    float sc = dinv[row];  // pre-scale rows by dinv -> agg loop needs no dinv[s]
#pragma unroll
                    for (int j = 0; j < 4; j++) {
                        int col = bn + wn + j * 16 + fc;
                        out[(size_t)(col >> 5) * M * 32 + (size_t)row * 32 + (col & 31)] =
                            (_Float16)(acc[i][j][r] * sc);
                    }
                }
            }
        }
    }
}

// ---------------- feature-tiled aggregation, 4 lanes/node x 16 nodes/wave ----------------
// in/out are [8][N][32] f16, rows pre-scaled by dinv. tile = blockIdx.x & 7 ->
// round-robin dispatch pins tile t to XCD t; per-XCD gather set = N*32*2B = 3.2MB < 4MB L2.
// Lane owns 8 features (16B); node = tid>>2, fq = tid&3. No cross-lane reduce.
// MODE 1: out = relu(acc*dd + bias)*dd   MODE 0: out = acc*dd
template <int MODE>
__global__ __launch_bounds__(256) void k_agg_t(const _Float16* __restrict__ in, _Float16* __restrict__ out,
                                               const float* __restrict__ dinv, const int* __restrict__ rowptr,
                                               const int* __restrict__ csr, const float* __restrict__ bias,
                                               int N) {
    const int tile = blockIdx.x & 7;
    const int g = (blockIdx.x >> 3) * 64 + (threadIdx.x >> 2);
    if (g >= N) return;
    const int fq = threadIdx.x & 3;  // feature-quarter: 8 f16 = 16B
    const _Float16* __restrict__ tin = in + (size_t)tile * N * 32 + fq * 8;

    const int beg = rowptr[g], end = rowptr[g + 1];

    float acc[8];
    {
        half8 sv = *(const half8*)(tin + (size_t)g * 32);  // self (pre-scaled)
#pragma unroll
        for (int j = 0; j < 8; j++) acc[j] = (float)sv[j];
    }
#pragma unroll 4
    for (int e = beg; e < end; ++e) {
        int s = csr[e];
        half8 v = *(const half8*)(tin + (size_t)s * 32);
#pragma unroll
        for (int j = 0; j < 8; j++) acc[j] += (float)v[j];
    }

    const float dd = dinv[g];
    half8 o;
    if (MODE) {
        const float4v* bp = (const float4v*)(bias + tile * 32 + fq * 8);
        float4v b0 = bp[0], b1 = bp[1];
#pragma unroll
        for (int j = 0; j < 4; j++) {
            o[j] = (_Float16)(fmaxf(acc[j] * dd + b0[j], 0.f) * dd);
            o[4 + j] = (_Float16)(fmaxf(acc[4 + j] * dd + b1[j], 0.f) * dd);
        }
    } else {
#pragma unroll
        for (int j = 0; j < 8; j++) o[j] = (_Float16)(acc[j] * dd);
    }
    *(half8*)(out + (size_t)tile * N * 32 + (size_t)g * 32 + fq * 8) = o;
}

// ---------------- launch ----------------

extern "C" void kernel_launch(void* const* d_in, const int* in_sizes, int n_in,
                              void* d_out, int out_size, void* d_ws, size_t ws_size,
                              hipStream_t stream) {
    const float* x   = (const float*)d_in[0];
    const int*   ei  = (const int*)d_in[1];
    const float* W1  = (const float*)d_in[2];
    const float* b1  = (const float*)d_in[3];
    const float* Wmu = (const float*)d_in[4];
    const float* bmu = (const float*)d_in[5];
    const float* Wls = (const float*)d_in[6];
    const float* bls = (const float*)d_in[7];
    const int N = in_sizes[0] / 256;
    const int E = in_sizes[1] / 2;
    const int* esrc = ei;
    const int* edst = ei + E;

    char* ws = (char*)d_ws;
    size_t off = 0;
    auto alloc = [&](size_t bytes) -> void* {
        void* p = ws + off;
        off += (bytes + 255) & ~(size_t)255;
        return p;
    };
    _Float16* h1  = (_Float16*)alloc((size_t)N * 256 * 2);  // tiled h1s (scaled); reused as g
    _Float16* hb  = (_Float16*)alloc((size_t)N * 256 * 2);  // tiled hbs (scaled)
    _Float16* Wt1 = (_Float16*)alloc(256 * 256 * 2);
    _Float16* Wct = (_Float16*)alloc(256 * 256 * 2);
    float* dinv   = (float*)alloc((size_t)N * 4);
    int* degcnt   = (int*)alloc((size_t)N * 2 * 4);  // [deg | rowcnt] contiguous -> one memset
    int* deg      = degcnt;
    int* rowcnt   = degcnt + N;
    int* rowptr   = (int*)alloc((size_t)(N + 1) * 4);
    int* bsum     = (int*)alloc(256 * 4);
    int* csr      = (int*)alloc((size_t)E * 4);

    const int nb = (N + 255) / 256;  // scan blocks (<=256)

    hipMemsetAsync(degcnt, 0, (size_t)N * 2 * 4, stream);

    const int nbe = 8 * ((E + 255) / 256);  // partitioned edge kernels
    k_deg<<<nbe, 256, 0, stream>>>(edst, deg, E, N);
    k_scan1<<<nb, 256, 0, stream>>>(deg, rowptr, bsum, dinv, N);
    k_scan2<<<1, 256, 0, stream>>>(bsum, rowptr, nb, N);
    k_scan3<<<nb, 256, 0, stream>>>(rowptr, bsum, N);
    k_fill<<<nbe, 256, 0, stream>>>(esrc, edst, rowptr, rowcnt, csr, E, N);
    k_wt<<<512, 256, 0, stream>>>(W1, Wmu, Wls, Wt1, Wct);

    const int nbm = (N + 127) / 128;
    const int nba = 8 * ((N + 63) / 64);
    gemm_k<1, 0><<<nbm * 2, 256, 0, stream>>>(x, Wt1, nullptr, nullptr, dinv, h1, N, 0);
    k_agg_t<1><<<nba, 256, 0, stream>>>(h1, hb, dinv, rowptr, csr, b1, N);
    k_agg_t<0><<<nba, 256, 0, stream>>>(hb, h1, dinv, rowptr, csr, nullptr, N);
    gemm_k<0, 1><<<nbm * 2, 256, 0, stream>>>(h1, Wct, bmu, bls, nullptr, d_out, N, (size_t)N * 128);
}

// Round 11
// 330.157 us; speedup vs baseline: 1.6604x; 1.0030x over previous
//
#include <hip/hip_runtime.h>
#include <hip/hip_fp16.h>

typedef __attribute__((ext_vector_type(8))) _Float16 half8;
typedef __attribute__((ext_vector_type(4))) _Float16 half4;
typedef __attribute__((ext_vector_type(4))) float float4v;

#define LDP2 72  // padded LDS row stride in f16 for BK=64 (144B -> stride 36 banks -> 2-way, free)

// ---------------- degree / CSR build ----------------
// k_deg: single unpartitioned pass (no bulk writes -> round-8 write-amp mechanism
// doesn't apply; partitioned version paid 8x edge-list re-read for nothing).
__global__ __launch_bounds__(256) void k_deg(const int* __restrict__ dst, int* __restrict__ deg, int E) {
    int e = blockIdx.x * 256 + threadIdx.x;
    if (e < E) atomicAdd(&deg[dst[e]], 1);
}

// k_fill: dst-range partitioned per XCD (proven: kills 17x csr write amplification).
__global__ __launch_bounds__(256) void k_fill(const int* __restrict__ src, const int* __restrict__ dst,
                                              const int* __restrict__ rowptr, int* __restrict__ rowcnt,
                                              int* __restrict__ csr, int E, int N) {
    const int part = blockIdx.x & 7;
    const int e = (blockIdx.x >> 3) * 256 + threadIdx.x;
    if (e >= E) return;
    const int lo = (int)(((long long)part * N) >> 3);
    const int hi = (int)(((long long)(part + 1) * N) >> 3);
    int d = dst[e];
    if (d >= lo && d < hi) {
        int pos = rowptr[d] + atomicAdd(&rowcnt[d], 1);
        csr[pos] = src[e];
    }
}

// ---- parallel exclusive scan of deg -> rowptr (3 phases), dinv fused into phase 1 ----

__global__ __launch_bounds__(256) void k_scan1(const int* __restrict__ deg, int* __restrict__ rowptr,
                                               int* __restrict__ bsum, float* __restrict__ dinv, int N) {
    __shared__ int sm[256];
    const int t = threadIdx.x;
    const int i = blockIdx.x * 256 + t;
    int v = (i < N) ? deg[i] : 0;
    if (i < N) dinv[i] = rsqrtf((float)(v + 1));  // +1 = self-loop
    int x = v;
    sm[t] = x;
    __syncthreads();
#pragma unroll
    for (int off = 1; off < 256; off <<= 1) {
        int y = (t >= off) ? sm[t - off] : 0;
        __syncthreads();
        x += y;
        sm[t] = x;
        __syncthreads();
    }
    if (i < N) rowptr[i] = x - v;      // exclusive within block
    if (t == 255) bsum[blockIdx.x] = x; // block total
}

__global__ __launch_bounds__(256) void k_scan2(int* __restrict__ bsum, int* __restrict__ rowptr, int nb, int N) {
    __shared__ int sm[256];
    const int t = threadIdx.x;
    int v = (t < nb) ? bsum[t] : 0;
    int x = v;
    sm[t] = x;
    __syncthreads();
#pragma unroll
    for (int off = 1; off < 256; off <<= 1) {
        int y = (t >= off) ? sm[t - off] : 0;
        __syncthreads();
        x += y;
        sm[t] = x;
        __syncthreads();
    }
    if (t < nb) bsum[t] = x - v;  // exclusive block offsets
    if (t == 255) rowptr[N] = x;  // grand total = E
}

__global__ __launch_bounds__(256) void k_scan3(int* __restrict__ rowptr, const int* __restrict__ bsum, int N) {
    int i = blockIdx.x * 256 + threadIdx.x;
    if (i < N) rowptr[i] += bsum[blockIdx.x];
}

// ---------------- weight prep: transpose + f16 convert ----------------
__global__ __launch_bounds__(256) void k_wt(const float* __restrict__ W1, const float* __restrict__ Wmu,
                                            const float* __restrict__ Wls, _Float16* __restrict__ Wt1,
                                            _Float16* __restrict__ Wct) {
    int b = blockIdx.x;
    int t = threadIdx.x;  // k index
    if (b < 256) {
        Wt1[b * 256 + t] = (_Float16)W1[t * 256 + b];
    } else {
        int j = b - 256;
        float v = (j < 128) ? Wmu[t * 128 + j] : Wls[t * 128 + (j - 128)];
        Wct[j * 256 + t] = (_Float16)v;
    }
}

// ---------------- GEMM: [M x 256] @ [256 x 256], BK=64, reg-prefetch staging ----------------
// f16 node-feature arrays use the FEATURE-TILED layout: [8 tiles][M][32 feats].
template <int AF32, int OUTF32>
__global__ __launch_bounds__(256) void gemm_k(const void* __restrict__ Aptr, const _Float16* __restrict__ Bt,
                                              const float* __restrict__ bmu, const float* __restrict__ bls,
                                              const float* __restrict__ dinv,
                                              void* __restrict__ outp, int M, size_t split) {
    __shared__ _Float16 As[128 * LDP2];
    __shared__ _Float16 Bs[128 * LDP2];
    const int t = threadIdx.x;
    const int lane = t & 63;
    const int wid = t >> 6;

    // bijective chunked XCD swizzle (assumes xcd = blockIdx.x % 8 round-robin)
    const int nwg = gridDim.x;
    const int wg = blockIdx.x;
    const int q8 = nwg >> 3, r8 = nwg & 7;
    const int xcd = wg & 7, pos = wg >> 3;
    const int v = (xcd < r8) ? (xcd * (q8 + 1) + pos) : (r8 * (q8 + 1) + (xcd - r8) * q8 + pos);
    const int bm = (v >> 1) * 128;
    const int bn = (v & 1) * 128;

    const int wm = (wid & 1) * 64;
    const int wn = (wid >> 1) * 64;

    float4v acc[4][4];
#pragma unroll
    for (int i = 0; i < 4; i++)
#pragma unroll
        for (int j = 0; j < 4; j++) acc[i][j] = (float4v){0.f, 0.f, 0.f, 0.f};

    // prefetch registers
    float4v ar32[8];
    half8 ar16[4];
    half8 br[4];

    const int a32row = t >> 1;
    const int a32ko = (t & 1) * 32;

    auto load_regs = [&](int kt) {
        if (AF32) {
            const float* A = (const float*)Aptr;
            int gr = bm + a32row; if (gr >= M) gr = M - 1;
            const float4v* p = (const float4v*)(A + (size_t)gr * 256 + kt + a32ko);
#pragma unroll
            for (int q = 0; q < 8; q++) ar32[q] = p[q];
        } else {
            const _Float16* A = (const _Float16*)Aptr;
#pragma unroll
            for (int m = 0; m < 4; m++) {
                int u = m * 256 + t;
                int row = u >> 3, k8 = (u & 7) * 8;
                int gr = bm + row; if (gr >= M) gr = M - 1;
                int k = kt + k8;  // feature index; tiled address
                ar16[m] = *(const half8*)(A + (size_t)(k >> 5) * M * 32 + (size_t)gr * 32 + (k & 31));
            }
        }
#pragma unroll
        for (int m = 0; m < 4; m++) {
            int u = m * 256 + t;
            int row = u >> 3, k8 = (u & 7) * 8;
            br[m] = *(const half8*)(Bt + (size_t)(bn + row) * 256 + kt + k8);
        }
    };

    auto write_lds = [&]() {
        if (AF32) {
#pragma unroll
            for (int q = 0; q < 4; q++) {
                half8 h;
#pragma unroll
                for (int j = 0; j < 4; j++) { h[j] = (_Float16)ar32[2 * q][j]; h[4 + j] = (_Float16)ar32[2 * q + 1][j]; }
                *(half8*)&As[a32row * LDP2 + a32ko + q * 8] = h;
            }
        } else {
#pragma unroll
            for (int m = 0; m < 4; m++) {
                int u = m * 256 + t;
                int row = u >> 3, k8 = (u & 7) * 8;
                *(half8*)&As[row * LDP2 + k8] = ar16[m];
            }
        }
#pragma unroll
        for (int m = 0; m < 4; m++) {
            int u = m * 256 + t;
            int row = u >> 3, k8 = (u & 7) * 8;
            *(half8*)&Bs[row * LDP2 + k8] = br[m];
        }
    };

    load_regs(0);
#pragma unroll
    for (int it = 0; it < 4; it++) {
        if (it > 0) __syncthreads();
        write_lds();
        __syncthreads();
        if (it < 3) load_regs((it + 1) * 64);  // next-tile loads hidden under MFMA

        const int kg = (lane >> 4) * 8;
        const int fr = lane & 15;
#pragma unroll
        for (int kk = 0; kk < 64; kk += 32) {
            half8 af[4], bf[4];
#pragma unroll
            for (int f = 0; f < 4; f++) af[f] = *(const half8*)&As[(wm + f * 16 + fr) * LDP2 + kk + kg];
#pragma unroll
            for (int f = 0; f < 4; f++) bf[f] = *(const half8*)&Bs[(wn + f * 16 + fr) * LDP2 + kk + kg];
#pragma unroll
            for (int i = 0; i < 4; i++)
#pragma unroll
                for (int j = 0; j < 4; j++)
                    acc[i][j] = __builtin_amdgcn_mfma_f32_16x16x32_f16(af[i], bf[j], acc[i][j], 0, 0, 0);
        }
    }

    // ---- epilogue: D mapping col=lane&15, row=(lane>>4)*4+reg ----
    const int fc = lane & 15;
    const int rq = (lane >> 4) * 4;
    if (OUTF32) {
        float* out = (float*)outp;
#pragma unroll
        for (int i = 0; i < 4; i++) {
#pragma unroll
            for (int j = 0; j < 4; j++) {
                int col = bn + wn + j * 16 + fc;
                float bias = (col < 128) ? bmu[col] : bls[col - 128];
#pragma unroll
                for (int r = 0; r < 4; r++) {
                    int row = bm + wm + i * 16 + rq + r;
                    if (row < M) {
                        size_t o = (col < 128) ? ((size_t)row * 128 + col)
                                               : (split + (size_t)row * 128 + (col - 128));
                        out[o] = acc[i][j][r] + bias;
                    }
                }
            }
        }
    } else {
        _Float16* out = (_Float16*)outp;
#pragma unroll
        for (int i = 0; i < 4; i++) {
#pragma unroll
            for (int r = 0; r < 4; r++) {
                int row = bm + wm + i * 16 + rq + r;
                if (row < M) {
                    float sc = dinv[row];  // pre-scale rows by dinv -> agg loop needs no dinv[s]
#pragma unroll
                    for (int j = 0; j < 4; j++) {
                        int col = bn + wn + j * 16 + fc;
                        out[(size_t)(col >> 5) * M * 32 + (size_t)row * 32 + (col & 31)] =
                            (_Float16)(acc[i][j][r] * sc);
                    }
                }
            }
        }
    }
}

// ---------------- feature-tiled aggregation, 4 lanes/node x 16 nodes/wave ----------------
// 2-stage software pipeline: rows(batch i+1) and csr(batch i+1) are in flight while
// accumulating batch i, so the serial csr->row L2-hit chain (~400cyc) is overlapped.
// MODE 1: out = relu(acc*dd + bias)*dd   MODE 0: out = acc*dd
template <int MODE>
__global__ __launch_bounds__(256) void k_agg_t(const _Float16* __restrict__ in, _Float16* __restrict__ out,
                                               const float* __restrict__ dinv, const int* __restrict__ rowptr,
                                               const int* __restrict__ csr, const float* __restrict__ bias,
                                               int N) {
    const int tile = blockIdx.x & 7;
    const int g = (blockIdx.x >> 3) * 64 + (threadIdx.x >> 2);
    if (g >= N) return;
    const int fq = threadIdx.x & 3;  // feature-quarter: 8 f16 = 16B
    const _Float16* __restrict__ tin = in + (size_t)tile * N * 32 + fq * 8;

    const int beg = rowptr[g], end = rowptr[g + 1];
    const int nb4 = (end - beg) >> 2;

    float acc[8];
    {
        half8 sv = *(const half8*)(tin + (size_t)g * 32);  // self (pre-scaled)
#pragma unroll
        for (int j = 0; j < 8; j++) acc[j] = (float)sv[j];
    }

    int e = beg;
    half8 r0, r1, r2, r3;
    if (nb4 > 0) {
        int i0 = csr[e], i1 = csr[e + 1], i2 = csr[e + 2], i3 = csr[e + 3];
        r0 = *(const half8*)(tin + (size_t)i0 * 32);
        r1 = *(const half8*)(tin + (size_t)i1 * 32);
        r2 = *(const half8*)(tin + (size_t)i2 * 32);
        r3 = *(const half8*)(tin + (size_t)i3 * 32);
    }
    for (int b = 0; b + 1 < nb4; ++b) {
        int n0 = csr[e + 4], n1 = csr[e + 5], n2 = csr[e + 6], n3 = csr[e + 7];
        half8 s0 = *(const half8*)(tin + (size_t)n0 * 32);
        half8 s1 = *(const half8*)(tin + (size_t)n1 * 32);
        half8 s2 = *(const half8*)(tin + (size_t)n2 * 32);
        half8 s3 = *(const half8*)(tin + (size_t)n3 * 32);
#pragma unroll
        for (int j = 0; j < 8; j++)
            acc[j] += (float)r0[j] + (float)r1[j] + (float)r2[j] + (float)r3[j];
        r0 = s0; r1 = s1; r2 = s2; r3 = s3;
        e += 4;
    }
    if (nb4 > 0) {
#pragma unroll
        for (int j = 0; j < 8; j++)
            acc[j] += (float)r0[j] + (float)r1[j] + (float)r2[j] + (float)r3[j];
        e += 4;
    }
    for (; e < end; ++e) {
        int s = csr[e];
        half8 v = *(const half8*)(tin + (size_t)s * 32);
#pragma unroll
        for (int j = 0; j < 8; j++) acc[j] += (float)v[j];
    }

    const float dd = dinv[g];
    half8 o;
    if (MODE) {
        const float4v* bp = (const float4v*)(bias + tile * 32 + fq * 8);
        float4v b0 = bp[0], b1 = bp[1];
#pragma unroll
        for (int j = 0; j < 4; j++) {
            o[j] = (_Float16)(fmaxf(acc[j] * dd + b0[j], 0.f) * dd);
            o[4 + j] = (_Float16)(fmaxf(acc[4 + j] * dd + b1[j], 0.f) * dd);
        }
    } else {
#pragma unroll
        for (int j = 0; j < 8; j++) o[j] = (_Float16)(acc[j] * dd);
    }
    *(half8*)(out + (size_t)tile * N * 32 + (size_t)g * 32 + fq * 8) = o;
}

// ---------------- launch ----------------

extern "C" void kernel_launch(void* const* d_in, const int* in_sizes, int n_in,
                              void* d_out, int out_size, void* d_ws, size_t ws_size,
                              hipStream_t stream) {
    const float* x   = (const float*)d_in[0];
    const int*   ei  = (const int*)d_in[1];
    const float* W1  = (const float*)d_in[2];
    const float* b1  = (const float*)d_in[3];
    const float* Wmu = (const float*)d_in[4];
    const float* bmu = (const float*)d_in[5];
    const float* Wls = (const float*)d_in[6];
    const float* bls = (const float*)d_in[7];
    const int N = in_sizes[0] / 256;
    const int E = in_sizes[1] / 2;
    const int* esrc = ei;
    const int* edst = ei + E;

    char* ws = (char*)d_ws;
    size_t off = 0;
    auto alloc = [&](size_t bytes) -> void* {
        void* p = ws + off;
        off += (bytes + 255) & ~(size_t)255;
        return p;
    };
    _Float16* h1  = (_Float16*)alloc((size_t)N * 256 * 2);  // tiled h1s (scaled); reused as g
    _Float16* hb  = (_Float16*)alloc((size_t)N * 256 * 2);  // tiled hbs (scaled)
    _Float16* Wt1 = (_Float16*)alloc(256 * 256 * 2);
    _Float16* Wct = (_Float16*)alloc(256 * 256 * 2);
    float* dinv   = (float*)alloc((size_t)N * 4);
    int* degcnt   = (int*)alloc((size_t)N * 2 * 4);  // [deg | rowcnt] contiguous -> one memset
    int* deg      = degcnt;
    int* rowcnt   = degcnt + N;
    int* rowptr   = (int*)alloc((size_t)(N + 1) * 4);
    int* bsum     = (int*)alloc(256 * 4);
    int* csr      = (int*)alloc((size_t)E * 4);

    const int nb = (N + 255) / 256;  // scan blocks (<=256)

    hipMemsetAsync(degcnt, 0, (size_t)N * 2 * 4, stream);

    k_deg<<<(E + 255) / 256, 256, 0, stream>>>(edst, deg, E);
    k_scan1<<<nb, 256, 0, stream>>>(deg, rowptr, bsum, dinv, N);
    k_scan2<<<1, 256, 0, stream>>>(bsum, rowptr, nb, N);
    k_scan3<<<nb, 256, 0, stream>>>(rowptr, bsum, N);
    const int nbe = 8 * ((E + 255) / 256);  // partitioned edge kernel
    k_fill<<<nbe, 256, 0, stream>>>(esrc, edst, rowptr, rowcnt, csr, E, N);
    k_wt<<<512, 256, 0, stream>>>(W1, Wmu, Wls, Wt1, Wct);

    const int nbm = (N + 127) / 128;
    const int nba = 8 * ((N + 63) / 64);
    gemm_k<1, 0><<<nbm * 2, 256, 0, stream>>>(x, Wt1, nullptr, nullptr, dinv, h1, N, 0);
    k_agg_t<1><<<nba, 256, 0, stream>>>(h1, hb, dinv, rowptr, csr, b1, N);
    k_agg_t<0><<<nba, 256, 0, stream>>>(hb, h1, dinv, rowptr, csr, nullptr, N);
    gemm_k<0, 1><<<nbm * 2, 256, 0, stream>>>(h1, Wct, bmu, bls, nullptr, d_out, N, (size_t)N * 128);
}